// Round 2
// baseline (418.011 us; speedup 1.0000x reference)
//
#include <hip/hip_runtime.h>

typedef unsigned short u16;
typedef u16 u16x8 __attribute__((ext_vector_type(8)));
typedef __bf16 bf16x8 __attribute__((ext_vector_type(8)));
typedef float f32x4 __attribute__((ext_vector_type(4)));

#define NE 8

// ---- helpers ----
__device__ __forceinline__ unsigned pk2(float a, float b) {
  unsigned ua = __builtin_bit_cast(unsigned, a) + 0x8000u;
  unsigned ub = __builtin_bit_cast(unsigned, b) + 0x8000u;
  return __builtin_amdgcn_perm(ub, ua, 0x07060302);
}
__device__ __forceinline__ u16 f2bf(float f) {
  return (u16)((__builtin_bit_cast(unsigned, f) + 0x8000u) >> 16);
}
__device__ __forceinline__ uint4 pk8(f32x4 a, f32x4 b) {
  return make_uint4(pk2(a[0], a[1]), pk2(a[2], a[3]),
                    pk2(b[0], b[1]), pk2(b[2], b[3]));
}
__device__ __forceinline__ bf16x8 ldfrag(const u16* p) {
  union { u16x8 u; bf16x8 b; } x;
  x.u = *(const u16x8*)p;
  return x.b;
}
// load 8 fp32 from LDS, convert -> bf16x8 fragment
__device__ __forceinline__ bf16x8 cvt8(const float* p) {
  f32x4 lo = *(const f32x4*)p;
  f32x4 hi = *(const f32x4*)(p + 4);
  union { uint4 u; bf16x8 b; } x;
  x.u = pk8(lo, hi);
  return x.b;
}
// async global->LDS, 16 B/lane: HW writes lane l at (uniform lds base) + l*16
__device__ __forceinline__ void gld16(const void* g, void* l) {
  __builtin_amdgcn_global_load_lds(
      (const __attribute__((address_space(1))) unsigned int*)g,
      (__attribute__((address_space(3))) unsigned int*)l, 16, 0, 0);
}

// ---- routing ----
__global__ __launch_bounds__(64) void routing_kernel(
    const float* __restrict__ x, const float* __restrict__ gw,
    const float* __restrict__ segw, int* __restrict__ counts,
    int* __restrict__ ptok, float* __restrict__ pw, float* __restrict__ sgate) {
  int t = blockIdx.x;
  int lane = threadIdx.x;
  const float* xr = x + (size_t)t * 2048;
  float s[NE];
#pragma unroll
  for (int e = 0; e < NE; e++) s[e] = 0.f;
  float sg = 0.f;
  for (int c = lane; c < 2048; c += 64) {
    float xv = xr[c];
#pragma unroll
    for (int e = 0; e < NE; e++) s[e] += xv * gw[e * 2048 + c];
    sg += xv * segw[c];
  }
#pragma unroll
  for (int off = 32; off > 0; off >>= 1) {
#pragma unroll
    for (int e = 0; e < NE; e++) s[e] += __shfl_down(s[e], off);
    sg += __shfl_down(sg, off);
  }
  if (lane == 0) {
    int i0 = 0;
#pragma unroll
    for (int e = 1; e < NE; e++) if (s[e] > s[i0]) i0 = e;
    int i1 = (i0 == 0) ? 1 : 0;
#pragma unroll
    for (int e = 0; e < NE; e++) if (e != i0 && s[e] > s[i1]) i1 = e;
    float r = __expf(s[i1] - s[i0]);
    float w0 = 1.f / (1.f + r);
    float w1 = 1.f - w0;
    int s0 = atomicAdd(&counts[i0], 1);
    ptok[(i0 << 9) + s0] = t; pw[(i0 << 9) + s0] = w0;
    int s1 = atomicAdd(&counts[i1], 1);
    ptok[(i1 << 9) + s1] = t; pw[(i1 << 9) + s1] = w1;
    sgate[t] = 1.f / (1.f + __expf(-sg));
  }
}

// ---- prep: x fp32 -> bf16 once ----
__global__ __launch_bounds__(256) void prep_kernel(
    const float* __restrict__ x, u16* __restrict__ xb) {
  int i = (blockIdx.x * 256 + threadIdx.x) * 32;
  const float* p = x + i;
  u16* o = xb + i;
#pragma unroll
  for (int s = 0; s < 4; s++) {
    f32x4 a = *(const f32x4*)(p + s * 8);
    f32x4 b = *(const f32x4*)(p + s * 8 + 4);
    *(uint4*)(o + s * 8) = pk8(a, b);
  }
}

// ---- gateup: M=128 x (16 gate + 16 up), BK=64, full K=2048, silu fused ----
// Depth-2 pipelined: double-buffered LDS, counted vmcnt, RAW s_barrier
// (no __syncthreads -> no vmcnt(0) drain). No cross-barrier register state.
__global__ __launch_bounds__(256) void gateup_kernel(
    const u16* __restrict__ xb, const float* __restrict__ Wg,
    const float* __restrict__ Wu, const float* __restrict__ SWg,
    const float* __restrict__ SWu, u16* __restrict__ hbufB,
    u16* __restrict__ hsB, const int* __restrict__ ptok,
    const int* __restrict__ counts) {
  __shared__ __align__(16) u16 As[2][128 * 64];    // 2 x 16 KB
  __shared__ __align__(16) float Bsf[2][32 * 64];  // 2 x 8 KB fp32

  int b = blockIdx.x;
  int t = threadIdx.x;
  int is_ex = (b < 2048);
  int e = 0, j, mt, cnt;
  const float *gW, *uW;
  u16* obase;
  if (is_ex) {
    e = b & 7; j = (b >> 3) & 63; mt = b >> 9;
    cnt = counts[e];
    if (mt * 128 >= cnt) return;
    gW = Wg + (size_t)(e * 1024 + j * 16) * 2048;
    uW = Wu + (size_t)(e * 1024 + j * 16) * 2048;
    obase = hbufB + (size_t)(e * 64 + j) * 8192;
  } else {
    // shared: same-j blocks pinned to one XCD (b%8) so weights fetch once
    int bs = b - 2048;
    int xcd = bs & 7; mt = (bs >> 3) & 3; j = (bs >> 5) * 8 + xcd; cnt = 512;
    gW = SWg + (size_t)(j * 16) * 2048;
    uW = SWu + (size_t)(j * 16) * 2048;
    obase = hsB + (size_t)j * 8192;
  }

  int lane = t & 63, wv = t >> 6;
  int quad = lane >> 4, l16 = lane & 15;

  // A staging: 16 chunks of 8 rows x 128 B; wave wv does chunks 4wv..4wv+3.
  const u16* aptr[4];
  int aoff[4];
#pragma unroll
  for (int i = 0; i < 4; i++) {
    int c = 4 * wv + i;
    int row = 8 * c + (lane >> 3);
    int slot = mt * 128 + row;
    int tok = is_ex ? ((slot < cnt) ? ptok[(e << 9) + slot] : 0) : slot;
    aptr[i] = xb + (size_t)tok * 2048 + (lane & 7) * 8;
    aoff[i] = c * 512;
  }
  // B staging: 8 chunks of 4 rows x 256 B; wave wv does chunks 2wv, 2wv+1.
  const float* bptr[2];
  int boff[2];
#pragma unroll
  for (int i = 0; i < 2; i++) {
    int c = 2 * wv + i;
    int rloc = 4 * c + (lane >> 4);
    const float* base = (rloc < 16) ? (gW + (size_t)rloc * 2048)
                                    : (uW + (size_t)(rloc - 16) * 2048);
    bptr[i] = base + (lane & 15) * 4;
    boff[i] = c * 256;
  }

#define STAGE_GU(kt, pb)                                                    \
  do {                                                                      \
    _Pragma("unroll") for (int i = 0; i < 4; i++)                           \
        gld16(aptr[i] + (kt) * 64, &As[pb][aoff[i]]);                       \
    _Pragma("unroll") for (int i = 0; i < 2; i++)                           \
        gld16(bptr[i] + (kt) * 64, &Bsf[pb][boff[i]]);                      \
  } while (0)

  f32x4 accg[2] = {}, accu[2] = {};

  STAGE_GU(0, 0);  // prologue: 6 loads in flight
  for (int kt = 0; kt < 32; kt++) {
    int pb = kt & 1;
    if (kt < 31) {
      STAGE_GU(kt + 1, pb ^ 1);                      // 12 in flight
      asm volatile("s_waitcnt vmcnt(6)" ::: "memory");  // tile kt landed
    } else {
      asm volatile("s_waitcnt vmcnt(0)" ::: "memory");
    }
    __builtin_amdgcn_s_barrier();       // all waves' tile-kt data visible
    __builtin_amdgcn_sched_barrier(0);  // rule 18: no hoist of ds_read
#pragma unroll
    for (int k2 = 0; k2 < 2; k2++) {
      bf16x8 af0 = ldfrag(&As[pb][(wv * 32 + l16) * 64 + k2 * 32 + quad * 8]);
      bf16x8 af1 = ldfrag(&As[pb][(wv * 32 + 16 + l16) * 64 + k2 * 32 + quad * 8]);
      bf16x8 bg = cvt8(&Bsf[pb][l16 * 64 + k2 * 32 + quad * 8]);
      bf16x8 bu = cvt8(&Bsf[pb][(16 + l16) * 64 + k2 * 32 + quad * 8]);
      accg[0] = __builtin_amdgcn_mfma_f32_16x16x32_bf16(af0, bg, accg[0], 0, 0, 0);
      accg[1] = __builtin_amdgcn_mfma_f32_16x16x32_bf16(af1, bg, accg[1], 0, 0, 0);
      accu[0] = __builtin_amdgcn_mfma_f32_16x16x32_bf16(af0, bu, accu[0], 0, 0, 0);
      accu[1] = __builtin_amdgcn_mfma_f32_16x16x32_bf16(af1, bu, accu[1], 0, 0, 0);
    }
    __builtin_amdgcn_sched_barrier(0);  // no sink of ds_read past barrier
    __builtin_amdgcn_s_barrier();       // buf pb free to overwrite next iter
  }
#undef STAGE_GU

  // epilogue: h = silu(g)*u -> blocked layout (contiguous 4-KB per block)
#pragma unroll
  for (int i = 0; i < 2; i++)
#pragma unroll
    for (int g = 0; g < 4; g++) {
      int rloc = wv * 32 + i * 16 + quad * 4 + g;
      int slot = mt * 128 + rloc;
      if (slot < cnt) {
        float gv = accg[i][g], uv = accu[i][g];
        float h = gv / (1.f + __expf(-gv)) * uv;
        obase[(size_t)slot * 16 + l16] = f2bf(h);
      }
    }
}

// ---- down expert: out[tok] += pw * (hbuf_e @ Wd_e^T), M=128 N=32 K=1024 ----
__global__ __launch_bounds__(256) void down_expert_kernel(
    const u16* __restrict__ hbufB, const float* __restrict__ Wd,
    float* __restrict__ out, const int* __restrict__ ptok,
    const float* __restrict__ pw, const int* __restrict__ counts) {
  __shared__ __align__(16) u16 As[2][4 * 128 * 16];  // 2 x 16 KB
  __shared__ __align__(16) float Bsf[2][32 * 64];    // 2 x 8 KB

  int b = blockIdx.x;
  int t = threadIdx.x;
  int e = b & 7, nt = (b >> 3) & 63, mt = b >> 9;
  int cnt = counts[e];
  if (mt * 128 >= cnt) return;

  int lane = t & 63, wv = t >> 6;
  int quad = lane >> 4, l16 = lane & 15;

  const u16* hb = hbufB + (size_t)e * 524288;  // e*64*8192

  const u16* aptr[4];
  int aoff[4];
#pragma unroll
  for (int i = 0; i < 4; i++) {
    aptr[i] = hb + (size_t)wv * 8192 + (size_t)(mt * 128 + i * 32 + (lane >> 1)) * 16
              + (lane & 1) * 8;
    aoff[i] = wv * 2048 + i * 512;
  }
  const float* bptr[2];
  int boff[2];
#pragma unroll
  for (int i = 0; i < 2; i++) {
    int c = 2 * wv + i;
    int rloc = 4 * c + (lane >> 4);
    bptr[i] = Wd + (size_t)(e * 2048 + nt * 32 + rloc) * 1024 + (lane & 15) * 4;
    boff[i] = c * 256;
  }

#define STAGE_DE(kt, pb)                                                    \
  do {                                                                      \
    _Pragma("unroll") for (int i = 0; i < 4; i++)                           \
        gld16(aptr[i] + (size_t)(kt) * 32768, &As[pb][aoff[i]]);            \
    _Pragma("unroll") for (int i = 0; i < 2; i++)                           \
        gld16(bptr[i] + (kt) * 64, &Bsf[pb][boff[i]]);                      \
  } while (0)

  f32x4 acc[2][2] = {};

  STAGE_DE(0, 0);
  for (int kt = 0; kt < 16; kt++) {
    int pb = kt & 1;
    if (kt < 15) {
      STAGE_DE(kt + 1, pb ^ 1);
      asm volatile("s_waitcnt vmcnt(6)" ::: "memory");
    } else {
      asm volatile("s_waitcnt vmcnt(0)" ::: "memory");
    }
    __builtin_amdgcn_s_barrier();
    __builtin_amdgcn_sched_barrier(0);
#pragma unroll
    for (int k2 = 0; k2 < 2; k2++) {
      int jsec = (k2 * 2 + (quad >> 1)) * 2048 + (quad & 1) * 8;
      bf16x8 af0 = ldfrag(&As[pb][jsec + (wv * 32 + l16) * 16]);
      bf16x8 af1 = ldfrag(&As[pb][jsec + (wv * 32 + 16 + l16) * 16]);
      bf16x8 b0 = cvt8(&Bsf[pb][l16 * 64 + k2 * 32 + quad * 8]);
      bf16x8 b1 = cvt8(&Bsf[pb][(16 + l16) * 64 + k2 * 32 + quad * 8]);
      acc[0][0] = __builtin_amdgcn_mfma_f32_16x16x32_bf16(af0, b0, acc[0][0], 0, 0, 0);
      acc[0][1] = __builtin_amdgcn_mfma_f32_16x16x32_bf16(af0, b1, acc[0][1], 0, 0, 0);
      acc[1][0] = __builtin_amdgcn_mfma_f32_16x16x32_bf16(af1, b0, acc[1][0], 0, 0, 0);
      acc[1][1] = __builtin_amdgcn_mfma_f32_16x16x32_bf16(af1, b1, acc[1][1], 0, 0, 0);
    }
    __builtin_amdgcn_sched_barrier(0);
    __builtin_amdgcn_s_barrier();
  }
#undef STAGE_DE

#pragma unroll
  for (int i = 0; i < 2; i++)
#pragma unroll
    for (int jf = 0; jf < 2; jf++)
#pragma unroll
      for (int g = 0; g < 4; g++) {
        int sl = mt * 128 + wv * 32 + i * 16 + quad * 4 + g;
        if (sl < cnt) {
          int tok = ptok[(e << 9) + sl];
          int col = nt * 32 + jf * 16 + l16;
          atomicAdd(&out[(size_t)tok * 2048 + col], pw[(e << 9) + sl] * acc[i][jf][g]);
        }
      }
}

// ---- down shared: out[row] = sgate[row] * (hs @ SWd^T), M=128 N=16 K=2048 ----
__global__ __launch_bounds__(256) void down_shared_kernel(
    const u16* __restrict__ hsB, const float* __restrict__ SWd,
    float* __restrict__ out, const float* __restrict__ sgate) {
  __shared__ __align__(16) u16 As[2][4 * 128 * 16];  // 2 x 16 KB
  __shared__ __align__(16) float Bsf[2][16 * 64];    // 2 x 4 KB

  int bs = blockIdx.x;
  int t = threadIdx.x;
  // same-nt blocks pinned to one XCD so SWd rows fetch once
  int xcd = bs & 7, mt = (bs >> 3) & 3, nt = (bs >> 5) * 8 + xcd;

  int lane = t & 63, wv = t >> 6;
  int quad = lane >> 4, l16 = lane & 15;

  const u16* aptr[4];
  int aoff[4];
#pragma unroll
  for (int i = 0; i < 4; i++) {
    aptr[i] = hsB + (size_t)wv * 8192 + (size_t)(mt * 128 + i * 32 + (lane >> 1)) * 16
              + (lane & 1) * 8;
    aoff[i] = wv * 2048 + i * 512;
  }
  const float* bptr = SWd + (size_t)(nt * 16 + 4 * wv + (lane >> 4)) * 2048
                      + (lane & 15) * 4;
  int boff = wv * 256;

#define STAGE_DS(kt, pb)                                                    \
  do {                                                                      \
    _Pragma("unroll") for (int i = 0; i < 4; i++)                           \
        gld16(aptr[i] + (size_t)(kt) * 32768, &As[pb][aoff[i]]);            \
    gld16(bptr + (kt) * 64, &Bsf[pb][boff]);                                \
  } while (0)

  f32x4 acc[2] = {};

  STAGE_DS(0, 0);
  for (int kt = 0; kt < 32; kt++) {
    int pb = kt & 1;
    if (kt < 31) {
      STAGE_DS(kt + 1, pb ^ 1);
      asm volatile("s_waitcnt vmcnt(5)" ::: "memory");
    } else {
      asm volatile("s_waitcnt vmcnt(0)" ::: "memory");
    }
    __builtin_amdgcn_s_barrier();
    __builtin_amdgcn_sched_barrier(0);
#pragma unroll
    for (int k2 = 0; k2 < 2; k2++) {
      int jsec = (k2 * 2 + (quad >> 1)) * 2048 + (quad & 1) * 8;
      bf16x8 af0 = ldfrag(&As[pb][jsec + (wv * 32 + l16) * 16]);
      bf16x8 af1 = ldfrag(&As[pb][jsec + (wv * 32 + 16 + l16) * 16]);
      bf16x8 bb = cvt8(&Bsf[pb][l16 * 64 + k2 * 32 + quad * 8]);
      acc[0] = __builtin_amdgcn_mfma_f32_16x16x32_bf16(af0, bb, acc[0], 0, 0, 0);
      acc[1] = __builtin_amdgcn_mfma_f32_16x16x32_bf16(af1, bb, acc[1], 0, 0, 0);
    }
    __builtin_amdgcn_sched_barrier(0);
    __builtin_amdgcn_s_barrier();
  }
#undef STAGE_DS

#pragma unroll
  for (int i = 0; i < 2; i++)
#pragma unroll
    for (int g = 0; g < 4; g++) {
      int row = mt * 128 + wv * 32 + i * 16 + quad * 4 + g;
      out[(size_t)row * 2048 + nt * 16 + l16] = sgate[row] * acc[i][g];
    }
}

extern "C" void kernel_launch(void* const* d_in, const int* in_sizes, int n_in,
                              void* d_out, int out_size, void* d_ws, size_t ws_size,
                              hipStream_t stream) {
  const float* x = (const float*)d_in[0];
  const float* gate_w = (const float*)d_in[1];
  const float* w_gate = (const float*)d_in[2];
  const float* w_up = (const float*)d_in[3];
  const float* w_down = (const float*)d_in[4];
  const float* sh_gate = (const float*)d_in[5];
  const float* sh_up = (const float*)d_in[6];
  const float* sh_down = (const float*)d_in[7];
  const float* se_gate_w = (const float*)d_in[8];
  float* out = (float*)d_out;

  char* ws = (char*)d_ws;
  int* counts = (int*)(ws + 0);                       // 32 B
  int* ptok = (int*)(ws + 1024);                      // 16 KB
  float* pw = (float*)(ws + 1024 + 16384);            // 16 KB
  float* sg = (float*)(ws + 1024 + 32768);            // 2 KB
  u16* xb = (u16*)(ws + 65536);                       // 2 MB
  u16* hbufB = (u16*)(ws + 65536 + (2u << 20));       // [e][j][512][16] = 8 MB
  u16* hsB = (u16*)(ws + 65536 + (10u << 20));        // [j][512][16] = 2 MB

  hipMemsetAsync(counts, 0, 32, stream);
  routing_kernel<<<512, 64, 0, stream>>>(x, gate_w, se_gate_w, counts, ptok, pw, sg);
  prep_kernel<<<128, 256, 0, stream>>>(x, xb);
  // gateup: expert 8e*64j*4mt = 2048 (live ~512) + shared 512
  gateup_kernel<<<2560, 256, 0, stream>>>(xb, w_gate, w_up, sh_gate, sh_up,
                                          hbufB, hsB, ptok, counts);
  // shared down first (plain store covers every out element) ...
  down_shared_kernel<<<512, 256, 0, stream>>>(hsB, sh_down, out, sg);
  // ... then expert down atomicAdds on top
  down_expert_kernel<<<2048, 256, 0, stream>>>(hbufB, w_down, out, ptok, pw, counts);
}

// Round 3
// 378.735 us; speedup vs baseline: 1.1037x; 1.1037x over previous
//
#include <hip/hip_runtime.h>

typedef unsigned short u16;
typedef u16 u16x8 __attribute__((ext_vector_type(8)));
typedef __bf16 bf16x8 __attribute__((ext_vector_type(8)));
typedef float f32x4 __attribute__((ext_vector_type(4)));

#define NE 8

// ---- helpers ----
__device__ __forceinline__ unsigned pk2(float a, float b) {
  unsigned ua = __builtin_bit_cast(unsigned, a) + 0x8000u;
  unsigned ub = __builtin_bit_cast(unsigned, b) + 0x8000u;
  return __builtin_amdgcn_perm(ub, ua, 0x07060302);
}
__device__ __forceinline__ u16 f2bf(float f) {
  return (u16)((__builtin_bit_cast(unsigned, f) + 0x8000u) >> 16);
}
__device__ __forceinline__ uint4 pk8(f32x4 a, f32x4 b) {
  return make_uint4(pk2(a[0], a[1]), pk2(a[2], a[3]),
                    pk2(b[0], b[1]), pk2(b[2], b[3]));
}
__device__ __forceinline__ bf16x8 ldfrag(const u16* p) {
  union { u16x8 u; bf16x8 b; } x;
  x.u = *(const u16x8*)p;
  return x.b;
}
// load 2x4 fp32 from (possibly non-adjacent, swizzled) LDS slots -> bf16x8
__device__ __forceinline__ bf16x8 cvt8s(const float* p0, const float* p1) {
  f32x4 lo = *(const f32x4*)p0;
  f32x4 hi = *(const f32x4*)p1;
  union { uint4 u; bf16x8 b; } x;
  x.u = pk8(lo, hi);
  return x.b;
}
// async global->LDS, 16 B/lane: HW writes lane l at (uniform lds base) + l*16
__device__ __forceinline__ void gld16(const void* g, void* l) {
  __builtin_amdgcn_global_load_lds(
      (const __attribute__((address_space(1))) unsigned int*)g,
      (__attribute__((address_space(3))) unsigned int*)l, 16, 0, 0);
}

// ---- routing ----
__global__ __launch_bounds__(64) void routing_kernel(
    const float* __restrict__ x, const float* __restrict__ gw,
    const float* __restrict__ segw, int* __restrict__ counts,
    int* __restrict__ ptok, float* __restrict__ pw, float* __restrict__ sgate) {
  int t = blockIdx.x;
  int lane = threadIdx.x;
  const float* xr = x + (size_t)t * 2048;
  float s[NE];
#pragma unroll
  for (int e = 0; e < NE; e++) s[e] = 0.f;
  float sg = 0.f;
  for (int c = lane; c < 2048; c += 64) {
    float xv = xr[c];
#pragma unroll
    for (int e = 0; e < NE; e++) s[e] += xv * gw[e * 2048 + c];
    sg += xv * segw[c];
  }
#pragma unroll
  for (int off = 32; off > 0; off >>= 1) {
#pragma unroll
    for (int e = 0; e < NE; e++) s[e] += __shfl_down(s[e], off);
    sg += __shfl_down(sg, off);
  }
  if (lane == 0) {
    int i0 = 0;
#pragma unroll
    for (int e = 1; e < NE; e++) if (s[e] > s[i0]) i0 = e;
    int i1 = (i0 == 0) ? 1 : 0;
#pragma unroll
    for (int e = 0; e < NE; e++) if (e != i0 && s[e] > s[i1]) i1 = e;
    float r = __expf(s[i1] - s[i0]);
    float w0 = 1.f / (1.f + r);
    float w1 = 1.f - w0;
    int s0 = atomicAdd(&counts[i0], 1);
    ptok[(i0 << 9) + s0] = t; pw[(i0 << 9) + s0] = w0;
    int s1 = atomicAdd(&counts[i1], 1);
    ptok[(i1 << 9) + s1] = t; pw[(i1 << 9) + s1] = w1;
    sgate[t] = 1.f / (1.f + __expf(-sg));
  }
}

// ---- prep: x fp32 -> bf16 once ----
__global__ __launch_bounds__(256) void prep_kernel(
    const float* __restrict__ x, u16* __restrict__ xb) {
  int i = (blockIdx.x * 256 + threadIdx.x) * 32;
  const float* p = x + i;
  u16* o = xb + i;
#pragma unroll
  for (int s = 0; s < 4; s++) {
    f32x4 a = *(const f32x4*)(p + s * 8);
    f32x4 b = *(const f32x4*)(p + s * 8 + 4);
    *(uint4*)(o + s * 8) = pk8(a, b);
  }
}

// ---- gateup: M=128 x (16 gate + 16 up), BK=64, full K=2048, silu fused ----
// Depth-2 pipelined + XOR-swizzled LDS (rule 21: swizzle the per-lane GLOBAL
// source since global_load_lds writes linearly; apply same XOR on the read).
// A: 16B-slot s of row r holds global seg s^(r&7)  -> quad reads spread 8 slots
// B: 16B-slot s of row r holds global seg s^(r&7)  (16 slots/row, fp32)
__global__ __launch_bounds__(256) void gateup_kernel(
    const u16* __restrict__ xb, const float* __restrict__ Wg,
    const float* __restrict__ Wu, const float* __restrict__ SWg,
    const float* __restrict__ SWu, u16* __restrict__ hbufB,
    u16* __restrict__ hsB, const int* __restrict__ ptok,
    const int* __restrict__ counts) {
  __shared__ __align__(16) u16 As[2][128 * 64];    // 2 x 16 KB
  __shared__ __align__(16) float Bsf[2][32 * 64];  // 2 x 8 KB fp32

  int b = blockIdx.x;
  int t = threadIdx.x;
  int is_ex = (b < 2048);
  int e = 0, j, mt, cnt;
  const float *gW, *uW;
  u16* obase;
  if (is_ex) {
    e = b & 7; j = (b >> 3) & 63; mt = b >> 9;
    cnt = counts[e];
    if (mt * 128 >= cnt) return;
    gW = Wg + (size_t)(e * 1024 + j * 16) * 2048;
    uW = Wu + (size_t)(e * 1024 + j * 16) * 2048;
    obase = hbufB + (size_t)(e * 64 + j) * 8192;
  } else {
    // shared: same-j blocks pinned to one XCD (b%8) so weights fetch once
    int bs = b - 2048;
    int xcd = bs & 7; mt = (bs >> 3) & 3; j = (bs >> 5) * 8 + xcd; cnt = 512;
    gW = SWg + (size_t)(j * 16) * 2048;
    uW = SWu + (size_t)(j * 16) * 2048;
    obase = hsB + (size_t)j * 8192;
  }

  int lane = t & 63, wv = t >> 6;
  int quad = lane >> 4, l16 = lane & 15;

  // A staging: 16 chunks of 8 rows x 128 B; wave wv does chunks 4wv..4wv+3.
  // row-in-chunk = lane>>3 (= row&7); global seg = (lane&7) ^ (row&7).
  const u16* aptr[4];
  int aoff[4];
#pragma unroll
  for (int i = 0; i < 4; i++) {
    int c = 4 * wv + i;
    int row = 8 * c + (lane >> 3);
    int slot = mt * 128 + row;
    int tok = is_ex ? ((slot < cnt) ? ptok[(e << 9) + slot] : 0) : slot;
    aptr[i] = xb + (size_t)tok * 2048 + (((lane & 7) ^ ((lane >> 3) & 7)) * 8);
    aoff[i] = c * 512;
  }
  // B staging: 8 chunks of 4 rows x 256 B; wave wv does chunks 2wv, 2wv+1.
  // rows 0-15 = gate, 16-31 = up. global seg = (lane&15) ^ (rloc&7).
  const float* bptr[2];
  int boff[2];
#pragma unroll
  for (int i = 0; i < 2; i++) {
    int c = 2 * wv + i;
    int rloc = 4 * c + (lane >> 4);
    const float* base = (rloc < 16) ? (gW + (size_t)rloc * 2048)
                                    : (uW + (size_t)(rloc - 16) * 2048);
    bptr[i] = base + (((lane & 15) ^ (rloc & 7)) * 4);
    boff[i] = c * 256;
  }

#define STAGE_GU(kt, pb)                                                    \
  do {                                                                      \
    _Pragma("unroll") for (int i = 0; i < 4; i++)                           \
        gld16(aptr[i] + (kt) * 64, &As[pb][aoff[i]]);                       \
    _Pragma("unroll") for (int i = 0; i < 2; i++)                           \
        gld16(bptr[i] + (kt) * 64, &Bsf[pb][boff[i]]);                      \
  } while (0)

  f32x4 accg[2] = {}, accu[2] = {};

  STAGE_GU(0, 0);  // prologue: 6 loads in flight
  for (int kt = 0; kt < 32; kt++) {
    int pb = kt & 1;
    if (kt < 31) {
      STAGE_GU(kt + 1, pb ^ 1);                      // 12 in flight
      asm volatile("s_waitcnt vmcnt(6)" ::: "memory");  // tile kt landed
    } else {
      asm volatile("s_waitcnt vmcnt(0)" ::: "memory");
    }
    __builtin_amdgcn_s_barrier();       // all waves' tile-kt data visible
    __builtin_amdgcn_sched_barrier(0);  // rule 18: no hoist of ds_read
#pragma unroll
    for (int k2 = 0; k2 < 2; k2++) {
      int sA = ((k2 * 4 + quad) ^ (l16 & 7)) * 8;                // u16 units
      int s0 = ((k2 * 8 + quad * 2) ^ (l16 & 7)) * 4;            // f32 units
      int s1 = ((k2 * 8 + quad * 2 + 1) ^ (l16 & 7)) * 4;
      bf16x8 af0 = ldfrag(&As[pb][(wv * 32 + l16) * 64 + sA]);
      bf16x8 af1 = ldfrag(&As[pb][(wv * 32 + 16 + l16) * 64 + sA]);
      bf16x8 bg = cvt8s(&Bsf[pb][l16 * 64 + s0], &Bsf[pb][l16 * 64 + s1]);
      bf16x8 bu = cvt8s(&Bsf[pb][(16 + l16) * 64 + s0],
                        &Bsf[pb][(16 + l16) * 64 + s1]);
      accg[0] = __builtin_amdgcn_mfma_f32_16x16x32_bf16(af0, bg, accg[0], 0, 0, 0);
      accg[1] = __builtin_amdgcn_mfma_f32_16x16x32_bf16(af1, bg, accg[1], 0, 0, 0);
      accu[0] = __builtin_amdgcn_mfma_f32_16x16x32_bf16(af0, bu, accu[0], 0, 0, 0);
      accu[1] = __builtin_amdgcn_mfma_f32_16x16x32_bf16(af1, bu, accu[1], 0, 0, 0);
    }
    __builtin_amdgcn_sched_barrier(0);  // no sink of ds_read past barrier
    __builtin_amdgcn_s_barrier();       // buf pb free to overwrite next iter
  }
#undef STAGE_GU

  // epilogue: h = silu(g)*u -> blocked layout (contiguous 4-KB per block)
#pragma unroll
  for (int i = 0; i < 2; i++)
#pragma unroll
    for (int g = 0; g < 4; g++) {
      int rloc = wv * 32 + i * 16 + quad * 4 + g;
      int slot = mt * 128 + rloc;
      if (slot < cnt) {
        float gv = accg[i][g], uv = accu[i][g];
        float h = gv / (1.f + __expf(-gv)) * uv;
        obase[(size_t)slot * 16 + l16] = f2bf(h);
      }
    }
}

// ---- down expert: out[tok] += pw * (hbuf_e @ Wd_e^T), M=128 N=32 K=1024 ----
// A swizzle: 16B-half h of slot s holds global half h ^ ((s>>2)&1)
// B swizzle: same as gateup B
__global__ __launch_bounds__(256) void down_expert_kernel(
    const u16* __restrict__ hbufB, const float* __restrict__ Wd,
    float* __restrict__ out, const int* __restrict__ ptok,
    const float* __restrict__ pw, const int* __restrict__ counts) {
  __shared__ __align__(16) u16 As[2][4 * 128 * 16];  // 2 x 16 KB
  __shared__ __align__(16) float Bsf[2][32 * 64];    // 2 x 8 KB

  int b = blockIdx.x;
  int t = threadIdx.x;
  int e = b & 7, nt = (b >> 3) & 63, mt = b >> 9;
  int cnt = counts[e];
  if (mt * 128 >= cnt) return;

  int lane = t & 63, wv = t >> 6;
  int quad = lane >> 4, l16 = lane & 15;

  const u16* hb = hbufB + (size_t)e * 524288;  // e*64*8192

  const u16* aptr[4];
  int aoff[4];
#pragma unroll
  for (int i = 0; i < 4; i++) {
    aptr[i] = hb + (size_t)wv * 8192 + (size_t)(mt * 128 + i * 32 + (lane >> 1)) * 16
              + (((lane & 1) ^ ((lane >> 3) & 1)) * 8);
    aoff[i] = wv * 2048 + i * 512;
  }
  const float* bptr[2];
  int boff[2];
#pragma unroll
  for (int i = 0; i < 2; i++) {
    int c = 2 * wv + i;
    int rloc = 4 * c + (lane >> 4);
    bptr[i] = Wd + (size_t)(e * 2048 + nt * 32 + rloc) * 1024
              + (((lane & 15) ^ (rloc & 7)) * 4);
    boff[i] = c * 256;
  }

#define STAGE_DE(kt, pb)                                                    \
  do {                                                                      \
    _Pragma("unroll") for (int i = 0; i < 4; i++)                           \
        gld16(aptr[i] + (size_t)(kt) * 32768, &As[pb][aoff[i]]);            \
    _Pragma("unroll") for (int i = 0; i < 2; i++)                           \
        gld16(bptr[i] + (kt) * 64, &Bsf[pb][boff[i]]);                      \
  } while (0)

  f32x4 acc[2][2] = {};

  STAGE_DE(0, 0);
  for (int kt = 0; kt < 16; kt++) {
    int pb = kt & 1;
    if (kt < 15) {
      STAGE_DE(kt + 1, pb ^ 1);
      asm volatile("s_waitcnt vmcnt(6)" ::: "memory");
    } else {
      asm volatile("s_waitcnt vmcnt(0)" ::: "memory");
    }
    __builtin_amdgcn_s_barrier();
    __builtin_amdgcn_sched_barrier(0);
#pragma unroll
    for (int k2 = 0; k2 < 2; k2++) {
      // A frag: j' = k2*2+(quad>>1), half (quad&1) ^ ((slot>>2)&1)
      int jsec = (k2 * 2 + (quad >> 1)) * 2048 + (((quad & 1) ^ ((l16 >> 2) & 1)) * 8);
      int s0 = ((k2 * 8 + quad * 2) ^ (l16 & 7)) * 4;
      int s1 = ((k2 * 8 + quad * 2 + 1) ^ (l16 & 7)) * 4;
      bf16x8 af0 = ldfrag(&As[pb][jsec + (wv * 32 + l16) * 16]);
      bf16x8 af1 = ldfrag(&As[pb][jsec + (wv * 32 + 16 + l16) * 16]);
      bf16x8 b0 = cvt8s(&Bsf[pb][l16 * 64 + s0], &Bsf[pb][l16 * 64 + s1]);
      bf16x8 b1 = cvt8s(&Bsf[pb][(16 + l16) * 64 + s0],
                        &Bsf[pb][(16 + l16) * 64 + s1]);
      acc[0][0] = __builtin_amdgcn_mfma_f32_16x16x32_bf16(af0, b0, acc[0][0], 0, 0, 0);
      acc[0][1] = __builtin_amdgcn_mfma_f32_16x16x32_bf16(af0, b1, acc[0][1], 0, 0, 0);
      acc[1][0] = __builtin_amdgcn_mfma_f32_16x16x32_bf16(af1, b0, acc[1][0], 0, 0, 0);
      acc[1][1] = __builtin_amdgcn_mfma_f32_16x16x32_bf16(af1, b1, acc[1][1], 0, 0, 0);
    }
    __builtin_amdgcn_sched_barrier(0);
    __builtin_amdgcn_s_barrier();
  }
#undef STAGE_DE

#pragma unroll
  for (int i = 0; i < 2; i++)
#pragma unroll
    for (int jf = 0; jf < 2; jf++)
#pragma unroll
      for (int g = 0; g < 4; g++) {
        int sl = mt * 128 + wv * 32 + i * 16 + quad * 4 + g;
        if (sl < cnt) {
          int tok = ptok[(e << 9) + sl];
          int col = nt * 32 + jf * 16 + l16;
          atomicAdd(&out[(size_t)tok * 2048 + col], pw[(e << 9) + sl] * acc[i][jf][g]);
        }
      }
}

// ---- down shared: out[row] = sgate[row] * (hs @ SWd^T), M=128 N=16 K=2048 ----
__global__ __launch_bounds__(256) void down_shared_kernel(
    const u16* __restrict__ hsB, const float* __restrict__ SWd,
    float* __restrict__ out, const float* __restrict__ sgate) {
  __shared__ __align__(16) u16 As[2][4 * 128 * 16];  // 2 x 16 KB
  __shared__ __align__(16) float Bsf[2][16 * 64];    // 2 x 4 KB

  int bs = blockIdx.x;
  int t = threadIdx.x;
  // same-nt blocks pinned to one XCD so SWd rows fetch once
  int xcd = bs & 7, mt = (bs >> 3) & 3, nt = (bs >> 5) * 8 + xcd;

  int lane = t & 63, wv = t >> 6;
  int quad = lane >> 4, l16 = lane & 15;

  const u16* aptr[4];
  int aoff[4];
#pragma unroll
  for (int i = 0; i < 4; i++) {
    aptr[i] = hsB + (size_t)wv * 8192 + (size_t)(mt * 128 + i * 32 + (lane >> 1)) * 16
              + (((lane & 1) ^ ((lane >> 3) & 1)) * 8);
    aoff[i] = wv * 2048 + i * 512;
  }
  int brloc = 4 * wv + (lane >> 4);
  const float* bptr = SWd + (size_t)(nt * 16 + brloc) * 2048
                      + (((lane & 15) ^ (brloc & 7)) * 4);
  int boff = wv * 256;

#define STAGE_DS(kt, pb)                                                    \
  do {                                                                      \
    _Pragma("unroll") for (int i = 0; i < 4; i++)                           \
        gld16(aptr[i] + (size_t)(kt) * 32768, &As[pb][aoff[i]]);            \
    gld16(bptr + (kt) * 64, &Bsf[pb][boff]);                                \
  } while (0)

  f32x4 acc[2] = {};

  STAGE_DS(0, 0);
  for (int kt = 0; kt < 32; kt++) {
    int pb = kt & 1;
    if (kt < 31) {
      STAGE_DS(kt + 1, pb ^ 1);
      asm volatile("s_waitcnt vmcnt(5)" ::: "memory");
    } else {
      asm volatile("s_waitcnt vmcnt(0)" ::: "memory");
    }
    __builtin_amdgcn_s_barrier();
    __builtin_amdgcn_sched_barrier(0);
#pragma unroll
    for (int k2 = 0; k2 < 2; k2++) {
      int jsec = (k2 * 2 + (quad >> 1)) * 2048 + (((quad & 1) ^ ((l16 >> 2) & 1)) * 8);
      int s0 = ((k2 * 8 + quad * 2) ^ (l16 & 7)) * 4;
      int s1 = ((k2 * 8 + quad * 2 + 1) ^ (l16 & 7)) * 4;
      bf16x8 af0 = ldfrag(&As[pb][jsec + (wv * 32 + l16) * 16]);
      bf16x8 af1 = ldfrag(&As[pb][jsec + (wv * 32 + 16 + l16) * 16]);
      bf16x8 bb = cvt8s(&Bsf[pb][l16 * 64 + s0], &Bsf[pb][l16 * 64 + s1]);
      acc[0] = __builtin_amdgcn_mfma_f32_16x16x32_bf16(af0, bb, acc[0], 0, 0, 0);
      acc[1] = __builtin_amdgcn_mfma_f32_16x16x32_bf16(af1, bb, acc[1], 0, 0, 0);
    }
    __builtin_amdgcn_sched_barrier(0);
    __builtin_amdgcn_s_barrier();
  }
#undef STAGE_DS

#pragma unroll
  for (int i = 0; i < 2; i++)
#pragma unroll
    for (int g = 0; g < 4; g++) {
      int row = mt * 128 + wv * 32 + i * 16 + quad * 4 + g;
      out[(size_t)row * 2048 + nt * 16 + l16] = sgate[row] * acc[i][g];
    }
}

extern "C" void kernel_launch(void* const* d_in, const int* in_sizes, int n_in,
                              void* d_out, int out_size, void* d_ws, size_t ws_size,
                              hipStream_t stream) {
  const float* x = (const float*)d_in[0];
  const float* gate_w = (const float*)d_in[1];
  const float* w_gate = (const float*)d_in[2];
  const float* w_up = (const float*)d_in[3];
  const float* w_down = (const float*)d_in[4];
  const float* sh_gate = (const float*)d_in[5];
  const float* sh_up = (const float*)d_in[6];
  const float* sh_down = (const float*)d_in[7];
  const float* se_gate_w = (const float*)d_in[8];
  float* out = (float*)d_out;

  char* ws = (char*)d_ws;
  int* counts = (int*)(ws + 0);                       // 32 B
  int* ptok = (int*)(ws + 1024);                      // 16 KB
  float* pw = (float*)(ws + 1024 + 16384);            // 16 KB
  float* sg = (float*)(ws + 1024 + 32768);            // 2 KB
  u16* xb = (u16*)(ws + 65536);                       // 2 MB
  u16* hbufB = (u16*)(ws + 65536 + (2u << 20));       // [e][j][512][16] = 8 MB
  u16* hsB = (u16*)(ws + 65536 + (10u << 20));        // [j][512][16] = 2 MB

  hipMemsetAsync(counts, 0, 32, stream);
  routing_kernel<<<512, 64, 0, stream>>>(x, gate_w, se_gate_w, counts, ptok, pw, sg);
  prep_kernel<<<128, 256, 0, stream>>>(x, xb);
  // gateup: expert 8e*64j*4mt = 2048 (live ~512) + shared 512
  gateup_kernel<<<2560, 256, 0, stream>>>(xb, w_gate, w_up, sh_gate, sh_up,
                                          hbufB, hsB, ptok, counts);
  // shared down first (plain store covers every out element) ...
  down_shared_kernel<<<512, 256, 0, stream>>>(hsB, sh_down, out, sg);
  // ... then expert down atomicAdds on top
  down_expert_kernel<<<2048, 256, 0, stream>>>(hbufB, w_down, out, ptok, pw, counts);
}

// Round 5
// 347.847 us; speedup vs baseline: 1.2017x; 1.0888x over previous
//
#include <hip/hip_runtime.h>

typedef unsigned short u16;
typedef u16 u16x8 __attribute__((ext_vector_type(8)));
typedef __bf16 bf16x8 __attribute__((ext_vector_type(8)));
typedef float f32x4 __attribute__((ext_vector_type(4)));

#define NE 8

// ---- helpers ----
__device__ __forceinline__ unsigned pk2(float a, float b) {
  unsigned ua = __builtin_bit_cast(unsigned, a) + 0x8000u;
  unsigned ub = __builtin_bit_cast(unsigned, b) + 0x8000u;
  return __builtin_amdgcn_perm(ub, ua, 0x07060302);
}
__device__ __forceinline__ u16 f2bf(float f) {
  return (u16)((__builtin_bit_cast(unsigned, f) + 0x8000u) >> 16);
}
__device__ __forceinline__ bf16x8 ldfrag(const u16* p) {
  union { u16x8 u; bf16x8 b; } x;
  x.u = *(const u16x8*)p;
  return x.b;
}
// async global->LDS, 16 B/lane: HW writes lane l at (uniform lds base) + l*16
__device__ __forceinline__ void gld16(const void* g, void* l) {
  __builtin_amdgcn_global_load_lds(
      (const __attribute__((address_space(1))) unsigned int*)g,
      (__attribute__((address_space(3))) unsigned int*)l, 16, 0, 0);
}
#define MFMA16 __builtin_amdgcn_mfma_f32_16x16x32_bf16

// ---- fused routing + x->bf16 prep ----
__global__ __launch_bounds__(64) void route_prep_kernel(
    const float* __restrict__ x, const float* __restrict__ gw,
    const float* __restrict__ segw, int* __restrict__ counts,
    int* __restrict__ ptok, float* __restrict__ pw, float* __restrict__ sgate,
    u16* __restrict__ xb) {
  int t = blockIdx.x;
  int lane = threadIdx.x;
  const float* xr = x + (size_t)t * 2048;
  u16* xbr = xb + (size_t)t * 2048;
  float s[NE];
#pragma unroll
  for (int e = 0; e < NE; e++) s[e] = 0.f;
  float sg = 0.f;
#pragma unroll
  for (int it = 0; it < 8; it++) {
    int c = it * 256 + lane * 4;
    f32x4 xv = *(const f32x4*)(xr + c);
    *(uint2*)(xbr + c) = make_uint2(pk2(xv[0], xv[1]), pk2(xv[2], xv[3]));
#pragma unroll
    for (int e = 0; e < NE; e++) {
      f32x4 wv4 = *(const f32x4*)(gw + e * 2048 + c);
      s[e] += xv[0] * wv4[0] + xv[1] * wv4[1] + xv[2] * wv4[2] + xv[3] * wv4[3];
    }
    f32x4 sv = *(const f32x4*)(segw + c);
    sg += xv[0] * sv[0] + xv[1] * sv[1] + xv[2] * sv[2] + xv[3] * sv[3];
  }
#pragma unroll
  for (int off = 32; off > 0; off >>= 1) {
#pragma unroll
    for (int e = 0; e < NE; e++) s[e] += __shfl_down(s[e], off);
    sg += __shfl_down(sg, off);
  }
  if (lane == 0) {
    int i0 = 0;
#pragma unroll
    for (int e = 1; e < NE; e++) if (s[e] > s[i0]) i0 = e;
    int i1 = (i0 == 0) ? 1 : 0;
#pragma unroll
    for (int e = 0; e < NE; e++) if (e != i0 && s[e] > s[i1]) i1 = e;
    float r = __expf(s[i1] - s[i0]);
    float w0 = 1.f / (1.f + r);
    float w1 = 1.f - w0;
    int s0 = atomicAdd(&counts[i0], 1);
    ptok[(i0 << 9) + s0] = t; pw[(i0 << 9) + s0] = w0;
    int s1 = atomicAdd(&counts[i1], 1);
    ptok[(i1 << 9) + s1] = t; pw[(i1 << 9) + s1] = w1;
    sgate[t] = 1.f / (1.f + __expf(-sg));
  }
}

// ---- gateup: M=128 x (16 gate + 16 up), BK=64, K=2048, silu fused ----
// A: bf16 via global_load_lds, XOR-swizzled source (slot s of row r holds
//    global seg s^(r&7)).  B: fp32 reg-staged, cvt->bf16 once, ds_write with
//    the same XOR swizzle.  One barrier per K-step (stage-issue / compute /
//    waited-write / barrier); depth-2 LDS double buffer, counted vmcnt.
__global__ __launch_bounds__(256) void gateup_kernel(
    const u16* __restrict__ xb, const float* __restrict__ Wg,
    const float* __restrict__ Wu, const float* __restrict__ SWg,
    const float* __restrict__ SWu, u16* __restrict__ hbufB,
    u16* __restrict__ hsB, const int* __restrict__ ptok,
    const int* __restrict__ counts) {
  __shared__ __align__(16) u16 As[2][128 * 64];  // 32 KB
  __shared__ __align__(16) u16 Bs[2][32 * 64];   // 8 KB bf16

  int b = blockIdx.x;
  int t = threadIdx.x;
  int is_ex = (b < 2048);
  int e = 0, j, mt, cnt;
  const float *gW, *uW;
  u16* obase;
  if (is_ex) {
    e = b & 7; j = (b >> 3) & 63; mt = b >> 9;
    cnt = counts[e];
    if (mt * 128 >= cnt) return;
    gW = Wg + (size_t)(e * 1024 + j * 16) * 2048;
    uW = Wu + (size_t)(e * 1024 + j * 16) * 2048;
    obase = hbufB + (size_t)(e * 64 + j) * 8192;
  } else {
    // shared: same-j blocks pinned to one XCD (b%8) so weights fetch once
    int bs = b - 2048;
    int xcd = bs & 7; mt = (bs >> 3) & 3; j = (bs >> 5) * 8 + xcd; cnt = 512;
    gW = SWg + (size_t)(j * 16) * 2048;
    uW = SWu + (size_t)(j * 16) * 2048;
    obase = hsB + (size_t)j * 8192;
  }

  int lane = t & 63, wv = t >> 6;
  int quad = lane >> 4, l16 = lane & 15;

  // A staging: 16 chunks of 8 rows x 128 B; wave wv does chunks 4wv..4wv+3.
  const u16* aptr[4];
  int aoff[4];
#pragma unroll
  for (int i = 0; i < 4; i++) {
    int c = 4 * wv + i;
    int row = 8 * c + (lane >> 3);
    int slot = mt * 128 + row;
    int tok = is_ex ? ((slot < cnt) ? ptok[(e << 9) + slot] : 0) : slot;
    aptr[i] = xb + (size_t)tok * 2048 + (((lane & 7) ^ ((lane >> 3) & 7)) * 8);
    aoff[i] = c * 512;
  }
  // B staging: wave wv owns rows 8wv..8wv+7 (2 units of 4 rows); lane l16
  // loads 16 B fp32 (4 floats) = bf16 8B-half h=l16 of the 128-B bf16 row.
  const float* bsrc[2];
  int bwr[2];
#pragma unroll
  for (int i = 0; i < 2; i++) {
    int rloc = wv * 8 + i * 4 + quad;
    const float* base = (rloc < 16) ? (gW + (size_t)rloc * 2048)
                                    : (uW + (size_t)(rloc - 16) * 2048);
    bsrc[i] = base + l16 * 4;
    bwr[i] = rloc * 64 + (((l16 >> 1) ^ (rloc & 7)) * 8) + ((l16 & 1) * 4);
  }

  f32x4 accg[2] = {}, accu[2] = {};

#define GU_ISSUE(kt1, nb)                                                   \
  f32x4 bv0 = *(const f32x4*)(bsrc[0] + (kt1) * 64);                        \
  f32x4 bv1 = *(const f32x4*)(bsrc[1] + (kt1) * 64);                        \
  _Pragma("unroll") for (int i = 0; i < 4; i++)                             \
      gld16(aptr[i] + (kt1) * 64, &As[nb][aoff[i]]);                        \
  __builtin_amdgcn_sched_barrier(0);

#define GU_FINISH(nb)                                                       \
  asm volatile("s_waitcnt vmcnt(4)" ::: "memory");                          \
  *(uint2*)(&Bs[nb][bwr[0]]) =                                              \
      make_uint2(pk2(bv0[0], bv0[1]), pk2(bv0[2], bv0[3]));                 \
  *(uint2*)(&Bs[nb][bwr[1]]) =                                              \
      make_uint2(pk2(bv1[0], bv1[1]), pk2(bv1[2], bv1[3]));                 \
  asm volatile("s_waitcnt vmcnt(0) lgkmcnt(0)" ::: "memory");               \
  __builtin_amdgcn_s_barrier();                                             \
  __builtin_amdgcn_sched_barrier(0);

#define GU_COMPUTE(pb)                                                      \
  _Pragma("unroll") for (int k2 = 0; k2 < 2; k2++) {                        \
    int sl = ((k2 * 4 + quad) ^ (l16 & 7)) * 8;                             \
    bf16x8 af0 = ldfrag(&As[pb][(wv * 32 + l16) * 64 + sl]);                \
    bf16x8 af1 = ldfrag(&As[pb][(wv * 32 + 16 + l16) * 64 + sl]);           \
    bf16x8 bg = ldfrag(&Bs[pb][l16 * 64 + sl]);                             \
    bf16x8 bu = ldfrag(&Bs[pb][(16 + l16) * 64 + sl]);                      \
    accg[0] = MFMA16(af0, bg, accg[0], 0, 0, 0);                            \
    accg[1] = MFMA16(af1, bg, accg[1], 0, 0, 0);                            \
    accu[0] = MFMA16(af0, bu, accu[0], 0, 0, 0);                            \
    accu[1] = MFMA16(af1, bu, accu[1], 0, 0, 0);                            \
  }

  { GU_ISSUE(0, 0); GU_FINISH(0); }
  int pb = 0;
  for (int kt = 0; kt < 31; kt++) {
    GU_ISSUE(kt + 1, pb ^ 1);
    GU_COMPUTE(pb);
    GU_FINISH(pb ^ 1);
    pb ^= 1;
  }
  GU_COMPUTE(pb);
#undef GU_ISSUE
#undef GU_FINISH
#undef GU_COMPUTE

  // epilogue: h = silu(g)*u -> blocked layout (contiguous 4-KB per block)
#pragma unroll
  for (int i = 0; i < 2; i++)
#pragma unroll
    for (int g = 0; g < 4; g++) {
      int rloc = wv * 32 + i * 16 + quad * 4 + g;
      int slot = mt * 128 + rloc;
      if (slot < cnt) {
        float gv = accg[i][g], uv = accu[i][g];
        float h = gv / (1.f + __expf(-gv)) * uv;
        obase[(size_t)slot * 16 + l16] = f2bf(h);
      }
    }
}

// ---- merged down: expert blocks [0,2048) + shared blocks [2048,2560) ----
// out is pre-zeroed; both paths atomicAdd, so they can share one dispatch.
__global__ __launch_bounds__(256) void down_kernel(
    const u16* __restrict__ hbufB, const u16* __restrict__ hsB,
    const float* __restrict__ Wd, const float* __restrict__ SWd,
    float* __restrict__ out, const int* __restrict__ ptok,
    const float* __restrict__ pw, const int* __restrict__ counts,
    const float* __restrict__ sgate) {
  __shared__ __align__(16) u16 As[2][4 * 128 * 16];  // 32 KB
  __shared__ __align__(16) u16 Bs[2][32 * 64];       // 8 KB

  int b = blockIdx.x;
  int t = threadIdx.x;
  int lane = t & 63, wv = t >> 6;
  int quad = lane >> 4, l16 = lane & 15;

  if (b < 2048) {
    // ---------------- expert: M=128 N=32 K=1024 ----------------
    int e = b & 7, nt = (b >> 3) & 63, mt = b >> 9;
    int cnt = counts[e];
    if (mt * 128 >= cnt) return;
    const u16* hb = hbufB + (size_t)e * 524288;

    const u16* aptr[4];
    int aoff[4];
#pragma unroll
    for (int i = 0; i < 4; i++) {
      aptr[i] = hb + (size_t)wv * 8192 +
                (size_t)(mt * 128 + i * 32 + (lane >> 1)) * 16 +
                (((lane & 1) ^ ((lane >> 3) & 1)) * 8);
      aoff[i] = wv * 2048 + i * 512;
    }
    const float* bsrc[2];
    int bwr[2];
#pragma unroll
    for (int i = 0; i < 2; i++) {
      int rloc = wv * 8 + i * 4 + quad;
      bsrc[i] = Wd + (size_t)(e * 2048 + nt * 32 + rloc) * 1024 + l16 * 4;
      bwr[i] = rloc * 64 + (((l16 >> 1) ^ (rloc & 7)) * 8) + ((l16 & 1) * 4);
    }

    f32x4 acc[2][2] = {};

#define DE_ISSUE(kt1, nb)                                                   \
  f32x4 bv0 = *(const f32x4*)(bsrc[0] + (kt1) * 64);                        \
  f32x4 bv1 = *(const f32x4*)(bsrc[1] + (kt1) * 64);                        \
  _Pragma("unroll") for (int i = 0; i < 4; i++)                             \
      gld16(aptr[i] + (size_t)(kt1) * 32768, &As[nb][aoff[i]]);             \
  __builtin_amdgcn_sched_barrier(0);

#define DE_FINISH(nb)                                                       \
  asm volatile("s_waitcnt vmcnt(4)" ::: "memory");                          \
  *(uint2*)(&Bs[nb][bwr[0]]) =                                              \
      make_uint2(pk2(bv0[0], bv0[1]), pk2(bv0[2], bv0[3]));                 \
  *(uint2*)(&Bs[nb][bwr[1]]) =                                              \
      make_uint2(pk2(bv1[0], bv1[1]), pk2(bv1[2], bv1[3]));                 \
  asm volatile("s_waitcnt vmcnt(0) lgkmcnt(0)" ::: "memory");               \
  __builtin_amdgcn_s_barrier();                                             \
  __builtin_amdgcn_sched_barrier(0);

#define DE_COMPUTE(pb)                                                      \
  _Pragma("unroll") for (int k2 = 0; k2 < 2; k2++) {                        \
    int jsec = (k2 * 2 + (quad >> 1)) * 2048 +                              \
               (((quad & 1) ^ ((l16 >> 2) & 1)) * 8);                       \
    int sl = ((k2 * 4 + quad) ^ (l16 & 7)) * 8;                             \
    bf16x8 af0 = ldfrag(&As[pb][jsec + (wv * 32 + l16) * 16]);              \
    bf16x8 af1 = ldfrag(&As[pb][jsec + (wv * 32 + 16 + l16) * 16]);         \
    bf16x8 b0 = ldfrag(&Bs[pb][l16 * 64 + sl]);                             \
    bf16x8 b1 = ldfrag(&Bs[pb][(16 + l16) * 64 + sl]);                      \
    acc[0][0] = MFMA16(af0, b0, acc[0][0], 0, 0, 0);                        \
    acc[0][1] = MFMA16(af0, b1, acc[0][1], 0, 0, 0);                        \
    acc[1][0] = MFMA16(af1, b0, acc[1][0], 0, 0, 0);                        \
    acc[1][1] = MFMA16(af1, b1, acc[1][1], 0, 0, 0);                        \
  }

    { DE_ISSUE(0, 0); DE_FINISH(0); }
    int pb = 0;
    for (int kt = 0; kt < 15; kt++) {
      DE_ISSUE(kt + 1, pb ^ 1);
      DE_COMPUTE(pb);
      DE_FINISH(pb ^ 1);
      pb ^= 1;
    }
    DE_COMPUTE(pb);
#undef DE_ISSUE
#undef DE_FINISH
#undef DE_COMPUTE

#pragma unroll
    for (int i = 0; i < 2; i++)
#pragma unroll
      for (int jf = 0; jf < 2; jf++)
#pragma unroll
        for (int g = 0; g < 4; g++) {
          int sl = mt * 128 + wv * 32 + i * 16 + quad * 4 + g;
          if (sl < cnt) {
            int tok = ptok[(e << 9) + sl];
            int col = nt * 32 + jf * 16 + l16;
            atomicAdd(&out[(size_t)tok * 2048 + col],
                      pw[(e << 9) + sl] * acc[i][jf][g]);
          }
        }
  } else {
    // ---------------- shared: M=128 N=16 K=2048 ----------------
    int bs = b - 2048;
    int xcd = bs & 7, mt = (bs >> 3) & 3, nt = (bs >> 5) * 8 + xcd;

    const u16* aptr[4];
    int aoff[4];
#pragma unroll
    for (int i = 0; i < 4; i++) {
      aptr[i] = hsB + (size_t)wv * 8192 +
                (size_t)(mt * 128 + i * 32 + (lane >> 1)) * 16 +
                (((lane & 1) ^ ((lane >> 3) & 1)) * 8);
      aoff[i] = wv * 2048 + i * 512;
    }
    int rloc = wv * 4 + quad;
    const float* bsrc = SWd + (size_t)(nt * 16 + rloc) * 2048 + l16 * 4;
    int bwr = rloc * 64 + (((l16 >> 1) ^ (rloc & 7)) * 8) + ((l16 & 1) * 4);

    f32x4 acc[2] = {};

#define DS_ISSUE(kt1, nb)                                                   \
  f32x4 bv0 = *(const f32x4*)(bsrc + (kt1) * 64);                           \
  _Pragma("unroll") for (int i = 0; i < 4; i++)                             \
      gld16(aptr[i] + (size_t)(kt1) * 32768, &As[nb][aoff[i]]);             \
  __builtin_amdgcn_sched_barrier(0);

#define DS_FINISH(nb)                                                       \
  asm volatile("s_waitcnt vmcnt(4)" ::: "memory");                          \
  *(uint2*)(&Bs[nb][bwr]) =                                                 \
      make_uint2(pk2(bv0[0], bv0[1]), pk2(bv0[2], bv0[3]));                 \
  asm volatile("s_waitcnt vmcnt(0) lgkmcnt(0)" ::: "memory");               \
  __builtin_amdgcn_s_barrier();                                             \
  __builtin_amdgcn_sched_barrier(0);

#define DS_COMPUTE(pb)                                                      \
  _Pragma("unroll") for (int k2 = 0; k2 < 2; k2++) {                        \
    int jsec = (k2 * 2 + (quad >> 1)) * 2048 +                              \
               (((quad & 1) ^ ((l16 >> 2) & 1)) * 8);                       \
    int sl = ((k2 * 4 + quad) ^ (l16 & 7)) * 8;                             \
    bf16x8 af0 = ldfrag(&As[pb][jsec + (wv * 32 + l16) * 16]);              \
    bf16x8 af1 = ldfrag(&As[pb][jsec + (wv * 32 + 16 + l16) * 16]);         \
    bf16x8 bb = ldfrag(&Bs[pb][l16 * 64 + sl]);                             \
    acc[0] = MFMA16(af0, bb, acc[0], 0, 0, 0);                              \
    acc[1] = MFMA16(af1, bb, acc[1], 0, 0, 0);                              \
  }

    { DS_ISSUE(0, 0); DS_FINISH(0); }
    int pb = 0;
    for (int kt = 0; kt < 31; kt++) {
      DS_ISSUE(kt + 1, pb ^ 1);
      DS_COMPUTE(pb);
      DS_FINISH(pb ^ 1);
      pb ^= 1;
    }
    DS_COMPUTE(pb);
#undef DS_ISSUE
#undef DS_FINISH
#undef DS_COMPUTE

#pragma unroll
    for (int i = 0; i < 2; i++)
#pragma unroll
      for (int g = 0; g < 4; g++) {
        int row = mt * 128 + wv * 32 + i * 16 + quad * 4 + g;
        atomicAdd(&out[(size_t)row * 2048 + nt * 16 + l16],
                  sgate[row] * acc[i][g]);
      }
  }
}

extern "C" void kernel_launch(void* const* d_in, const int* in_sizes, int n_in,
                              void* d_out, int out_size, void* d_ws, size_t ws_size,
                              hipStream_t stream) {
  const float* x = (const float*)d_in[0];
  const float* gate_w = (const float*)d_in[1];
  const float* w_gate = (const float*)d_in[2];
  const float* w_up = (const float*)d_in[3];
  const float* w_down = (const float*)d_in[4];
  const float* sh_gate = (const float*)d_in[5];
  const float* sh_up = (const float*)d_in[6];
  const float* sh_down = (const float*)d_in[7];
  const float* se_gate_w = (const float*)d_in[8];
  float* out = (float*)d_out;

  char* ws = (char*)d_ws;
  int* counts = (int*)(ws + 0);                       // 32 B
  int* ptok = (int*)(ws + 1024);                      // 16 KB
  float* pw = (float*)(ws + 1024 + 16384);            // 16 KB
  float* sg = (float*)(ws + 1024 + 32768);            // 2 KB
  u16* xb = (u16*)(ws + 65536);                       // 2 MB
  u16* hbufB = (u16*)(ws + 65536 + (2u << 20));       // [e][j][512][16] = 8 MB
  u16* hsB = (u16*)(ws + 65536 + (10u << 20));        // [j][512][16] = 2 MB

  hipMemsetAsync(counts, 0, 32, stream);
  hipMemsetAsync(out, 0, out_size, stream);
  route_prep_kernel<<<512, 64, 0, stream>>>(x, gate_w, se_gate_w, counts,
                                            ptok, pw, sg, xb);
  // gateup: expert 8e*64j*4mt = 2048 (live ~700) + shared 512
  gateup_kernel<<<2560, 256, 0, stream>>>(xb, w_gate, w_up, sh_gate, sh_up,
                                          hbufB, hsB, ptok, counts);
  // merged down: expert 2048 (live ~700) + shared 512, all atomicAdd on
  // pre-zeroed out -> no ordering needed, tails overlap
  down_kernel<<<2560, 256, 0, stream>>>(hbufB, hsB, w_down, sh_down, out,
                                        ptok, pw, counts, sg);
}